// Round 4
// baseline (629.003 us; speedup 1.0000x reference)
//
#include <hip/hip_runtime.h>
#include <cstdint>

// Shapes (fixed): B=4, L=512, H=8, Dk=Dv=64, dm=512

typedef __attribute__((ext_vector_type(8))) short short8;   // 8 bf16 (4 VGPRs)
typedef __attribute__((ext_vector_type(4))) float f32x4;    // MFMA accumulator

__device__ __forceinline__ unsigned short f2bf(float f){
  union { float f; unsigned u; } v; v.f = f;
  unsigned r = (v.u + 0x7fffu + ((v.u >> 16) & 1u)) >> 16;
  return (unsigned short)r;
}

__device__ __forceinline__ short8 ld8(const unsigned short* p){
  return *(const short8*)p;
}

__device__ __forceinline__ f32x4 mfma16(short8 a, short8 b, f32x4 c){
  return __builtin_amdgcn_mfma_f32_16x16x32_bf16(a, b, c, 0, 0, 0);
}

__device__ __forceinline__ float gelu_tanh(float x){
  float u = 0.7978845608028654f * (x + 0.044715f * x * x * x);
  return 0.5f * x * (1.f + tanhf(u));
}

// ---- MTx64-per-wave GEMM inner loop (MT*4 independent MFMA chains) ----
template<int MT, int LDA, int LDB, int KSTEPS>
__device__ __forceinline__ void gemmT(const unsigned short* __restrict__ A,
                                      const unsigned short* __restrict__ Bp,
                                      f32x4 acc[MT][4]){
#pragma unroll 2
  for (int ks = 0; ks < KSTEPS; ks++){
    int kk = ks * 32;
    short8 a[MT], b[4];
#pragma unroll
    for (int i = 0; i < MT; i++) a[i] = ld8(A + (size_t)i * 16 * LDA + kk);
#pragma unroll
    for (int j = 0; j < 4; j++)  b[j] = ld8(Bp + (size_t)j * 16 * LDB + kk);
#pragma unroll
    for (int i = 0; i < MT; i++)
#pragma unroll
      for (int j = 0; j < 4; j++)
        acc[i][j] = mfma16(a[i], b[j], acc[i][j]);
  }
}

// ---- fused prep: convert q,k,v f32->bf16 AND transpose+convert 6 weights ----
__global__ __launch_bounds__(256) void k_prep(const float* __restrict__ q,
    const float* __restrict__ k, const float* __restrict__ v,
    unsigned short* __restrict__ xin,
    const float* __restrict__ wqs, const float* __restrict__ wks,
    const float* __restrict__ wvs, const float* __restrict__ wself,
    const float* __restrict__ wdd, const float* __restrict__ wfc,
    unsigned short* __restrict__ Wt){
  int blk = blockIdx.x;
  int t = threadIdx.x;
  if (blk < 3072){
    int i = blk * 256 + t;                       // float4 units
    int w = i >> 18, r = i & 262143;
    const float* src = (w == 0) ? q : (w == 1) ? k : v;
    float4 f = *(const float4*)(src + (size_t)r * 4);
    unsigned lo = (unsigned)f2bf(f.x) | ((unsigned)f2bf(f.y) << 16);
    unsigned hi = (unsigned)f2bf(f.z) | ((unsigned)f2bf(f.w) << 16);
    uint2 o; o.x = lo; o.y = hi;
    *(uint2*)(xin + (size_t)w * 1048576 + (size_t)r * 4) = o;
  } else {
    int i = (blk - 3072) * 256 + t;              // 0..49151
    int w = i >> 13;
    int rr = i & 8191;
    int kg = rr >> 9;
    int n  = rr & 511;
    int k0 = kg * 32;
    const float* src = (w == 0) ? wqs : (w == 1) ? wks : (w == 2) ? wvs :
                       (w == 3) ? wself : (w == 4) ? wdd : wfc;
    unsigned pk[16];
#pragma unroll
    for (int j = 0; j < 16; j++){
      float a = src[(size_t)(k0 + 2 * j) * 512 + n];
      float b = src[(size_t)(k0 + 2 * j + 1) * 512 + n];
      pk[j] = (unsigned)f2bf(a) | ((unsigned)f2bf(b) << 16);
    }
    uint4* o4 = (uint4*)(Wt + (size_t)w * 262144 + (size_t)n * 512 + k0);
    o4[0] = make_uint4(pk[0],  pk[1],  pk[2],  pk[3]);
    o4[1] = make_uint4(pk[4],  pk[5],  pk[6],  pk[7]);
    o4[2] = make_uint4(pk[8],  pk[9],  pk[10], pk[11]);
    o4[3] = make_uint4(pk[12], pk[13], pk[14], pk[15]);
  }
}

// ---- fused projection GEMMs: 3x [2048,512]@[512,512], 32x64 per wave ----
__global__ __launch_bounds__(256) void k_proj(const unsigned short* __restrict__ xin,
    const unsigned short* __restrict__ Wt, unsigned short* __restrict__ qsb,
    unsigned short* __restrict__ khb, unsigned short* __restrict__ vhT){
  int wid = blockIdx.x * 4 + (threadIdx.x >> 6);    // 0..1535
  int mode = wid >> 9;                              // 0,1,2
  int tile = wid & 511;
  int tm = tile >> 3, tn = tile & 7;
  int lane = threadIdx.x & 63;
  int r = lane & 15, qq = lane >> 4;
  const unsigned short* X = xin + (size_t)mode * 1048576;
  const unsigned short* W = Wt + (size_t)mode * 262144;
  unsigned short* dst = (mode == 0) ? qsb : (mode == 1) ? khb : vhT;
  const unsigned short* A  = X + (size_t)(tm * 32 + r) * 512 + qq * 8;
  const unsigned short* Bp = W + (size_t)(tn * 64 + r) * 512 + qq * 8;
  f32x4 acc[2][4] = {};
  gemmT<2, 512, 512, 16>(A, Bp, acc);
  float scv = (mode == 0) ? 0.125f : 1.0f;
  int h = tn;
#pragma unroll
  for (int i = 0; i < 2; i++)
#pragma unroll
    for (int j = 0; j < 4; j++)
#pragma unroll
      for (int e = 0; e < 4; e++){
        int row = tm * 32 + i * 16 + qq * 4 + e;
        int d = j * 16 + r;
        int bb = row >> 9, l = row & 511;
        unsigned short val = f2bf(acc[i][j][e] * scv);
        size_t idx = (mode == 2) ? ((size_t)((bb * 8 + h) * 64 + d) * 512 + l)
                                 : ((size_t)((bb * 8 + h) * 512 + l) * 64 + d);
        dst[idx] = val;
      }
}

// ---- content scores: per (b,h): qs[512,64] @ kh[512,64]^T, 64x64 per wave ----
__global__ __launch_bounds__(256) void k_scores(const unsigned short* __restrict__ qs,
    const unsigned short* __restrict__ kh, float* __restrict__ attnF){
  int wid = blockIdx.x * 4 + (threadIdx.x >> 6);    // 0..2047
  int bh = wid >> 6;
  int tile = wid & 63;
  int tm = tile >> 3, tn = tile & 7;
  int lane = threadIdx.x & 63;
  int r = lane & 15, qq = lane >> 4;
  const unsigned short* A  = qs + (size_t)bh * 32768 + (size_t)(tm * 64 + r) * 64 + qq * 8;
  const unsigned short* Bp = kh + (size_t)bh * 32768 + (size_t)(tn * 64 + r) * 64 + qq * 8;
  f32x4 acc[4][4] = {};
  gemmT<4, 64, 64, 2>(A, Bp, acc);
  float* C = attnF + (size_t)bh * 262144;
#pragma unroll
  for (int i = 0; i < 4; i++)
#pragma unroll
    for (int j = 0; j < 4; j++)
#pragma unroll
      for (int e = 0; e < 4; e++){
        int row = tm * 64 + i * 16 + qq * 4 + e;
        int col = tn * 64 + j * 16 + r;
        C[(size_t)row * 512 + col] = acc[i][j][e];
      }
}

// ---- rel scores: compacted gather, coalesced per-wave LDS staging ----
__global__ __launch_bounds__(256) void k_relsoft(const unsigned short* __restrict__ qs,
    const float* __restrict__ vak, const int* __restrict__ adj,
    float* __restrict__ attnF, unsigned short* __restrict__ attn_bf){
  int bid = blockIdx.x;
  int b = bid >> 9, l = bid & 511;
  int t = threadIdx.x, lane = t & 63, w = t >> 6;
  __shared__ __align__(16) unsigned short qsA[16 * 64];
  __shared__ __align__(16) unsigned short vkt[4][16 * 72];  // per-wave stage
  __shared__ float sc[8 * 512];
  __shared__ short Mlist[512];
  __shared__ int lds4[4];
  for (int j = 0; j < 4; j++){
    int e = t + j * 256;
    int m = e >> 6, d = e & 63;
    qsA[e] = (m < 8) ? qs[((size_t)((b * 8 + m) * 512 + l)) * 64 + d] : (unsigned short)0;
  }
  int am0 = adj[(size_t)bid * 512 + t];
  int am1 = adj[(size_t)bid * 512 + t + 256];
  for (int j = 0; j < 16; j++){
    int e = t + j * 256;
    int h = e >> 9, m = e & 511;
    float s = attnF[((size_t)(b * 8 + h) * 512 + l) * 512 + m];
    int msk = (j & 1) ? am1 : am0;
    sc[e] = msk ? s : -10000.0f;                 // pre-apply mask
  }
  // prefix-scan adj -> compacted index list (increasing m)
  int2 av2 = *(const int2*)(adj + (size_t)bid * 512 + 2 * t);
  int c = av2.x + av2.y;
  int incl = c;
  for (int off = 1; off < 64; off <<= 1){
    int n = __shfl_up(incl, off, 64);
    if (lane >= off) incl += n;
  }
  if (lane == 63) lds4[w] = incl;
  __syncthreads();
  int base = 0;
  for (int i = 0; i < w; i++) base += lds4[i];
  int cnt = lds4[0] + lds4[1] + lds4[2] + lds4[3];
  int excl = base + incl - c;
  if (av2.x){ Mlist[excl] = (short)(2 * t); excl++; }
  if (av2.y){ Mlist[excl] = (short)(2 * t + 1); }
  int padded = (cnt + 31) & ~31;
  for (int i2 = cnt + t; i2 < padded; i2 += 256) Mlist[i2] = 0;
  __syncthreads();
  int r = lane & 15, qq = lane >> 4;
  short8 a0 = ld8(qsA + r * 64 + qq * 8);
  short8 a1 = ld8(qsA + r * 64 + 32 + qq * 8);
  const float* vrow = vak + (size_t)bid * 32768;
  int ntiles = (cnt + 15) >> 4;
  unsigned short* vw = &vkt[w][0];
  for (int tile = w; tile < ntiles; tile += 4){
    int rows0 = tile * 16;
    // stage 16 gathered rows: 16 consecutive lanes cover one row contiguously
#pragma unroll
    for (int it = 0; it < 4; it++){
      int idx = it * 64 + lane;                 // 0..255
      int rloc = idx >> 4, seg = idx & 15;
      int ms = Mlist[rows0 + rloc];
      float4 f = *(const float4*)(vrow + (size_t)ms * 64 + seg * 4);
      ushort4 u;
      u.x = f2bf(f.x); u.y = f2bf(f.y); u.z = f2bf(f.z); u.w = f2bf(f.w);
      *(ushort4*)(vw + rloc * 72 + seg * 4) = u;
    }
    int gi = rows0 + r;
    int m = Mlist[gi];
    const unsigned short* bp = vw + r * 72 + qq * 8;
    f32x4 acc = {0.f, 0.f, 0.f, 0.f};
    acc = mfma16(a0, ld8(bp),      acc);
    acc = mfma16(a1, ld8(bp + 32), acc);
    if (qq < 2){
#pragma unroll
      for (int i = 0; i < 4; i++){
        int h = qq * 4 + i;
        if (gi < cnt) sc[h * 512 + m] += acc[i];
      }
    }
  }
  __syncthreads();
  // softmax: wave w handles rows 2w, 2w+1 (mask already applied in sc)
  for (int hh = 0; hh < 2; hh++){
    int h = w * 2 + hh;
    float v[8]; float mx = -3.0e38f;
    for (int i = 0; i < 8; i++){
      int m = lane + i * 64;
      v[i] = sc[h * 512 + m]; mx = fmaxf(mx, v[i]);
    }
    for (int off = 32; off; off >>= 1) mx = fmaxf(mx, __shfl_xor(mx, off, 64));
    float sum = 0.f;
    for (int i = 0; i < 8; i++){ v[i] = __expf(v[i] - mx); sum += v[i]; }
    for (int off = 32; off; off >>= 1) sum += __shfl_xor(sum, off, 64);
    float inv = 1.f / sum;
    size_t base2 = ((size_t)(b * 8 + h) * 512 + l) * 512;
    for (int i = 0; i < 8; i++){
      int m = lane + i * 64;
      float p2 = v[i] * inv;
      attnF[base2 + m] = p2;
      attn_bf[base2 + m] = f2bf(p2);
    }
  }
}

// ---- out content: per (b,h): attn[512,512] @ vh[512,64], 32x64 per wave ----
__global__ __launch_bounds__(256) void k_outc(const unsigned short* __restrict__ attn_bf,
    const unsigned short* __restrict__ vhT, float* __restrict__ qc){
  int wid = blockIdx.x * 4 + (threadIdx.x >> 6);    // 0..511
  int bh = wid >> 4;
  int tm = wid & 15;
  int lane = threadIdx.x & 63;
  int r = lane & 15, qq = lane >> 4;
  const unsigned short* A  = attn_bf + (size_t)bh * 262144 + (size_t)(tm * 32 + r) * 512 + qq * 8;
  const unsigned short* Bp = vhT + (size_t)bh * 32768 + (size_t)r * 512 + qq * 8;
  f32x4 acc[2][4] = {};
  gemmT<2, 512, 512, 16>(A, Bp, acc);
  int b = bh >> 3, h = bh & 7;
#pragma unroll
  for (int i = 0; i < 2; i++)
#pragma unroll
    for (int j = 0; j < 4; j++)
#pragma unroll
      for (int e = 0; e < 4; e++){
        int lrow = tm * 32 + i * 16 + qq * 4 + e;
        int d = j * 16 + r;
        qc[(size_t)(b * 512 + lrow) * 512 + h * 64 + d] = acc[i][j][e];
      }
}

// ---- out rel: compacted gather + chunked coalesced transpose staging ----
__global__ __launch_bounds__(256) void k_outrel(const unsigned short* __restrict__ attn_bf,
    const float* __restrict__ vav, const float* __restrict__ qc,
    const int* __restrict__ adj, const float* __restrict__ wnw,
    unsigned short* __restrict__ qc_bf, float* __restrict__ nw, float* __restrict__ invden){
  int bid = blockIdx.x;
  int b = bid >> 9, l = bid & 511;
  int t = threadIdx.x, lane = t & 63, w = t >> 6;
  __shared__ __align__(16) unsigned short attnL[8][512];
  __shared__ __align__(16) unsigned short pAg[8][512];
  __shared__ __align__(16) unsigned short vvT[64 * 136];
  __shared__ short Mlist[512];
  __shared__ float orL[512];
  __shared__ float redf[4];
  __shared__ int lds4[4];
  int r = lane & 15, qq = lane >> 4;
  int h8 = r & 7;
  // stage attn rows (8 heads) coalesced
#pragma unroll
  for (int h = 0; h < 8; h++){
    const unsigned short* rowp = attn_bf + (((size_t)(b * 8 + h) * 512 + l) * 512);
    *(ushort2*)(&attnL[h][2 * t]) = *(const ushort2*)(rowp + 2 * t);
  }
  // prefix-scan adj -> compacted index list
  int2 av2 = *(const int2*)(adj + (size_t)bid * 512 + 2 * t);
  int c = av2.x + av2.y;
  int incl = c;
  for (int off = 1; off < 64; off <<= 1){
    int n = __shfl_up(incl, off, 64);
    if (lane >= off) incl += n;
  }
  if (lane == 63) lds4[w] = incl;
  __syncthreads();
  int base = 0;
  for (int i = 0; i < w; i++) base += lds4[i];
  int cnt = lds4[0] + lds4[1] + lds4[2] + lds4[3];
  int excl = base + incl - c;
  if (av2.x){ Mlist[excl] = (short)(2 * t); excl++; }
  if (av2.y){ Mlist[excl] = (short)(2 * t + 1); }
  int cntV = cnt;
  __syncthreads();
  if (cnt == 0){                                   // all-masked row: uniform attn
    for (int i2 = t; i2 < 512; i2 += 256) Mlist[i2] = (short)i2;
    cntV = 512;
    __syncthreads();                               // uniform condition -> legal
  }
  int padded = (cntV + 127) & ~127;                // chunk multiple (<=512)
  for (int i2 = cntV + t; i2 < padded; i2 += 256) Mlist[i2] = 0;
  __syncthreads();
  // build packed attn-gather operand (pads = 0)
  for (int j = t; j < padded; j += 256){
    int m = Mlist[j];
    bool vld = (j < cntV);
#pragma unroll
    for (int h = 0; h < 8; h++)
      pAg[h][j] = vld ? attnL[h][m] : (unsigned short)0;
  }
  __syncthreads();
  const float* vrow = vav + (size_t)bid * 32768;
  int dcol = w * 16 + r;
  f32x4 acc = {0.f, 0.f, 0.f, 0.f};
  int nchunks = padded >> 7;
  for (int ch = 0; ch < nchunks; ch++){
    // stage 128 gathered rows, coalesced reads, transposed LDS store
#pragma unroll
    for (int it = 0; it < 8; it++){
      int i4 = it * 256 + t;                       // 0..2047
      int mloc = i4 >> 4, d4 = (i4 & 15) * 4;
      int ms = Mlist[ch * 128 + mloc];
      float4 f = *(const float4*)(vrow + (size_t)ms * 64 + d4);
      vvT[(d4    ) * 136 + mloc] = f2bf(f.x);
      vvT[(d4 + 1) * 136 + mloc] = f2bf(f.y);
      vvT[(d4 + 2) * 136 + mloc] = f2bf(f.z);
      vvT[(d4 + 3) * 136 + mloc] = f2bf(f.w);
    }
    __syncthreads();
#pragma unroll
    for (int s = 0; s < 4; s++){
      short8 av = ld8(&pAg[h8][ch * 128 + s * 32 + qq * 8]);
      short8 bv = ld8(vvT + (size_t)dcol * 136 + s * 32 + qq * 8);
      acc = mfma16(av, bv, acc);
    }
    __syncthreads();
  }
  if (qq < 2){
#pragma unroll
    for (int i = 0; i < 4; i++){
      int h = qq * 4 + i;
      orL[h * 64 + dcol] = acc[i];
    }
  }
  __syncthreads();
  float part = 0.f;
  for (int j = 0; j < 2; j++){
    int e = t + j * 256;
    float val = qc[(size_t)bid * 512 + e] + orL[e];
    qc_bf[(size_t)bid * 512 + e] = f2bf(val);
    part += val * wnw[e];
  }
  for (int off = 32; off; off >>= 1) part += __shfl_xor(part, off, 64);
  if (lane == 0) redf[w] = part;
  __syncthreads();
  if (t == 0){
    float tot = redf[0] + redf[1] + redf[2] + redf[3];
    nw[bid] = 1.f / (1.f + __expf(-tot));
    invden[bid] = 1.f / ((cnt >= 1) ? (float)cnt : 1.f);
  }
}

// ---- fused post: selfi GEMM + ddT GEMM (transposed scatter) + ddw build ----
__global__ __launch_bounds__(256) void k_post(const unsigned short* __restrict__ qcb,
    const unsigned short* __restrict__ Wself, const unsigned short* __restrict__ Wdd,
    float* __restrict__ selfi, unsigned short* __restrict__ ddT,
    const int* __restrict__ adj, const float* __restrict__ nw,
    const float* __restrict__ invden, unsigned short* __restrict__ ddw){
  int blk = blockIdx.x;
  int t = threadIdx.x;
  if (blk < 256){
    int mode = blk >> 7;                          // 0: selfi, 1: ddT
    int wid = (blk & 127) * 4 + (t >> 6);         // 0..511
    int tm = wid >> 3, tn = wid & 7;
    int lane = t & 63;
    int r = lane & 15, qq = lane >> 4;
    const unsigned short* W = mode ? Wdd : Wself;
    const unsigned short* A  = qcb + (size_t)(tm * 32 + r) * 512 + qq * 8;
    const unsigned short* Bp = W + (size_t)(tn * 64 + r) * 512 + qq * 8;
    f32x4 acc[2][4] = {};
    gemmT<2, 512, 512, 16>(A, Bp, acc);
#pragma unroll
    for (int i = 0; i < 2; i++)
#pragma unroll
      for (int j = 0; j < 4; j++)
#pragma unroll
        for (int e = 0; e < 4; e++){
          int row = tm * 32 + i * 16 + qq * 4 + e;
          int col = tn * 64 + j * 16 + r;
          if (mode == 0)
            selfi[(size_t)row * 512 + col] = acc[i][j][e];
          else {
            int bb = row >> 9, m = row & 511;
            ddT[((size_t)(bb * 512 + col)) * 512 + m] = f2bf(acc[i][j][e]);
          }
        }
  } else {
    int i8 = ((blk - 256) * 256 + t) * 8;
    int bb = i8 >> 18, rest = i8 & 262143;
    int l = rest >> 9, m0 = rest & 511;
    int4 a0 = *(const int4*)(adj + i8);
    int4 a1 = *(const int4*)(adj + i8 + 4);
    float id = invden[bb * 512 + l];
    const float* nwb = nw + bb * 512 + m0;
    short8 o;
    o[0] = a0.x ? (short)f2bf(nwb[0] * id) : (short)0;
    o[1] = a0.y ? (short)f2bf(nwb[1] * id) : (short)0;
    o[2] = a0.z ? (short)f2bf(nwb[2] * id) : (short)0;
    o[3] = a0.w ? (short)f2bf(nwb[3] * id) : (short)0;
    o[4] = a1.x ? (short)f2bf(nwb[4] * id) : (short)0;
    o[5] = a1.y ? (short)f2bf(nwb[5] * id) : (short)0;
    o[6] = a1.z ? (short)f2bf(nwb[6] * id) : (short)0;
    o[7] = a1.w ? (short)f2bf(nwb[7] * id) : (short)0;
    *(short8*)(ddw + i8) = o;
  }
}

// ---- agg GEMM per b: ddw[512,512]@ddT^T + selfi -> xbf, 32x64 per wave ----
__global__ __launch_bounds__(256) void k_agg(const unsigned short* __restrict__ ddw,
    const unsigned short* __restrict__ ddT, const float* __restrict__ selfi,
    unsigned short* __restrict__ xbf){
  int wid = blockIdx.x * 4 + (threadIdx.x >> 6);   // 0..511
  int b = wid >> 7;
  int tile = wid & 127;
  int tm = tile >> 3, tn = tile & 7;
  int lane = threadIdx.x & 63;
  int r = lane & 15, qq = lane >> 4;
  const unsigned short* A  = ddw + (size_t)b * 262144 + (size_t)(tm * 32 + r) * 512 + qq * 8;
  const unsigned short* Bp = ddT + (size_t)b * 262144 + (size_t)(tn * 64 + r) * 512 + qq * 8;
  f32x4 acc[2][4] = {};
  gemmT<2, 512, 512, 16>(A, Bp, acc);
#pragma unroll
  for (int i = 0; i < 2; i++)
#pragma unroll
    for (int j = 0; j < 4; j++)
#pragma unroll
      for (int e = 0; e < 4; e++){
        int row = b * 512 + tm * 32 + i * 16 + qq * 4 + e;
        int col = tn * 64 + j * 16 + r;
        float x = acc[i][j][e] + selfi[(size_t)row * 512 + col];
        xbf[(size_t)row * 512 + col] = f2bf(x);
      }
}

// ---- final: xbf@Wfc -> gelu -> + residual -> qo f32, 32x64 per wave ----
__global__ __launch_bounds__(256) void k_fc(const unsigned short* __restrict__ xbf,
    const unsigned short* __restrict__ W, const float* __restrict__ qin,
    float* __restrict__ qo){
  int wid = blockIdx.x * 4 + (threadIdx.x >> 6);   // 0..511
  int tm = wid >> 3, tn = wid & 7;
  int lane = threadIdx.x & 63;
  int r = lane & 15, qq = lane >> 4;
  const unsigned short* A  = xbf + (size_t)(tm * 32 + r) * 512 + qq * 8;
  const unsigned short* Bp = W + (size_t)(tn * 64 + r) * 512 + qq * 8;
  f32x4 acc[2][4] = {};
  gemmT<2, 512, 512, 16>(A, Bp, acc);
#pragma unroll
  for (int i = 0; i < 2; i++)
#pragma unroll
    for (int j = 0; j < 4; j++)
#pragma unroll
      for (int e = 0; e < 4; e++){
        int row = tm * 32 + i * 16 + qq * 4 + e;
        int col = tn * 64 + j * 16 + r;
        qo[(size_t)row * 512 + col] = qin[(size_t)row * 512 + col] + gelu_tanh(acc[i][j][e]);
      }
}

extern "C" void kernel_launch(void* const* d_in, const int* in_sizes, int n_in,
                              void* d_out, int out_size, void* d_ws, size_t ws_size,
                              hipStream_t stream){
  const float* q    = (const float*)d_in[0];
  const float* k    = (const float*)d_in[1];
  const float* v    = (const float*)d_in[2];
  const float* vak  = (const float*)d_in[3];
  const float* vav  = (const float*)d_in[4];
  const int*   adjk = (const int*)d_in[5];
  // d_in[6] = adj_v: unused by the reference
  const float* wqs  = (const float*)d_in[7];
  const float* wks  = (const float*)d_in[8];
  const float* wvs  = (const float*)d_in[9];
  const float* wfc  = (const float*)d_in[10];
  const float* wnw  = (const float*)d_in[11];
  const float* wself= (const float*)d_in[12];
  const float* wdd  = (const float*)d_in[13];

  float* qo    = (float*)d_out;               // [4,512,512]
  float* attnF = qo + 1048576;                // [4,8,512,512]

  char* p = (char*)d_ws;
  unsigned short* xin   = (unsigned short*)p; p += 6291456;   // q,k,v bf16
  unsigned short* Wt    = (unsigned short*)p; p += 3145728;   // 6 transposed weights bf16
  unsigned short* qsb   = (unsigned short*)p; p += 2097152;   // [B,H,L,D]
  unsigned short* khb   = (unsigned short*)p; p += 2097152;   // [B,H,L,D]
  unsigned short* vhT   = (unsigned short*)p; p += 2097152;   // [B,H,D,L]
  unsigned short* attnb = (unsigned short*)p; p += 16777216;  // [B,H,L,L] bf16
  float*          qc    = (float*)p;          p += 4194304;   // [2048,512]
  unsigned short* qcb   = (unsigned short*)p; p += 2097152;
  float*          nw    = (float*)p;          p += 8192;
  float*          invd  = (float*)p;          p += 8192;
  float*          selfi = (float*)p;          p += 4194304;
  unsigned short* ddT   = (unsigned short*)p; p += 2097152;   // [B, n, m] bf16
  unsigned short* ddw   = (unsigned short*)p; p += 2097152;   // [B, l, m] bf16
  unsigned short* xbf   = (unsigned short*)p; p += 2097152;

  k_prep<<<3264, 256, 0, stream>>>(q, k, v, xin, wqs, wks, wvs, wself, wdd, wfc, Wt);
  k_proj<<<384, 256, 0, stream>>>(xin, Wt, qsb, khb, vhT);
  k_scores<<<512, 256, 0, stream>>>(qsb, khb, attnF);
  k_relsoft<<<2048, 256, 0, stream>>>(qsb, vak, adjk, attnF, attnb);
  k_outc<<<128, 256, 0, stream>>>(attnb, vhT, qc);
  k_outrel<<<2048, 256, 0, stream>>>(attnb, vav, qc, adjk, wnw, qcb, nw, invd);
  k_post<<<768, 256, 0, stream>>>(qcb, Wt + 786432, Wt + 1048576, selfi, ddT,
                                  adjk, nw, invd, ddw);
  k_agg<<<128, 256, 0, stream>>>(ddw, ddT, selfi, xbf);
  k_fc<<<128, 256, 0, stream>>>(xbf, Wt + 1310720, q, qo);
}